// Round 2
// baseline (161.458 us; speedup 1.0000x reference)
//
#include <hip/hip_runtime.h>

#define VOCAB 100000
#define EMBED 128
#define MAX_PATH 20
#define BATCH 32768
#define WPB 2                    // waves per block (block = 128 threads)
#define EPW 16                   // elements per wave (software pipeline)
#define NBLK (BATCH / (WPB * EPW))   // 1024 blocks -> 4 blocks/CU, all resident

// R10: software-pipelined gather engine. R9 falsified "occupancy-capped":
// occ 52->66% with flat BW (VGPR 24 => compiler serialized reg gathers).
// Real limiter = per-wave serial chain (ct -> meta -> gather) with one elem
// per wave. Fix: each wave processes 16 elems, depth-2 pipeline:
//  - prologue: ALL center/target for the wave's 16 elems loaded in 2
//    coalesced instrs, distributed via __shfl -> chain level 1 gone.
//  - iter k: issue meta(k+2) (10 lane-dependent vector loads; cannot
//    scalarize to SMEM so vmcnt counting stays exact), issue gathers(k+1)
//    (4 reg loads chunks 0,1 + 7 global_load_lds: h + chunks 2,3,4 into
//    LDS double buffer), then counted s_waitcnt vmcnt(21) = exactly the
//    21 newer instrs (10+11) left in flight -> gathers(k) complete with
//    ~1 full iteration of latency cover. Never vmcnt(0) in the loop.
//  - sched_barrier(0) pins each issue block + the wait (rule #18; also
//    keeps the vmcnt arithmetic exact against sinking).
//  - no conditional skips: uniform pipeline, fixed instr counts. Padded
//    chunks gather row 0 (L1-hot); cd==0 zeroes their contribution.
// Occupancy is LOW by design (8 waves/CU) but each wave keeps ~10KB+
// continuously in flight -> latency covered by MLP, not TLP.
constexpr unsigned VMW(unsigned n) {          // vmcnt(n), lgkm/exp free
    return 0x0F70u | (n & 0xFu) | ((n >> 4) << 14);
}

#define GLDS(SRC, DST)                                                        \
    __builtin_amdgcn_global_load_lds(                                         \
        (const __attribute__((address_space(1))) unsigned int*)(SRC),         \
        (__attribute__((address_space(3))) unsigned int*)(DST), 16, 0, 0)

__global__ __launch_bounds__(128, 4) void hs_loss_kernel(
    const int* __restrict__ center, const int* __restrict__ target,
    const float* __restrict__ in_emb, const float* __restrict__ inner_vec,
    const int* __restrict__ paths, const float* __restrict__ codes,
    float* __restrict__ partials)
{
    // per wave, per buffer: h (64 f4, row duplicated) + 3 chunks (128 f4 each)
    __shared__ float4 lds4[WPB][2][448];     // 28 KB
    __shared__ float  ws[WPB];

    const int wave = threadIdx.x >> 6;
    const int lane = threadIdx.x & 63;
    const int g    = lane >> 4;   // group 0..3
    const int gl   = lane & 15;   // lane within group
    const int w    = blockIdx.x * WPB + wave;     // 0..2047
    const int b0   = w * EPW;

    // ---- prologue: all ct for this wave's 16 elems (2 coalesced loads)
    const int cvec = center[b0 + (lane & 15)];
    const int tvec = target[b0 + (lane & 15)];

    int   p[EPW][5];
    float cd[EPW][5];
    float4 rg[EPW][4];

    // meta issue for elem e: 10 lane-dependent vector loads (addr uses g)
    auto issue_meta = [&](int e) {
        const int t_e = __shfl(tvec, e, 64);
        const int mb  = t_e * MAX_PATH + g;
        #pragma unroll
        for (int j = 0; j < 5; ++j) {
            p[e][j]  = paths[mb + 4 * j];
            cd[e][j] = codes[mb + 4 * j];
        }
    };

    // gather issue for elem e: 4 reg loads (chunks 0,1) + 7 global_load_lds
    auto issue_G = [&](int e) {
        const int c_e = __shfl(cvec, e, 64);
        const float4* v0 = (const float4*)(inner_vec + (size_t)p[e][0] * EMBED);
        const float4* v1 = (const float4*)(inner_vec + (size_t)p[e][1] * EMBED);
        rg[e][0] = v0[gl];  rg[e][1] = v0[gl + 16];
        rg[e][2] = v1[gl];  rg[e][3] = v1[gl + 16];
        float4* dst = &lds4[wave][e & 1][0];
        const float* hsrc = in_emb + (size_t)c_e * EMBED + 4 * (lane & 31);
        GLDS(hsrc, dst);                              // h row (dup'd to 1KB)
        #pragma unroll
        for (int cn = 0; cn < 3; ++cn) {
            const float* src = inner_vec + (size_t)p[e][cn + 2] * EMBED + 4 * gl;
            GLDS(src,      dst + 64 + cn * 128);
            GLDS(src + 64, dst + 64 + cn * 128 + 64);
        }
    };

    float acc = 0.f;
    auto do_compute = [&](int k) {
        const float4* buf = &lds4[wave][k & 1][0];
        const float4 h0 = buf[gl];
        const float4 h1 = buf[gl + 16];
        #pragma unroll
        for (int j = 0; j < 5; ++j) {
            float4 a0, a1;
            if (j < 2) { a0 = rg[k][2 * j]; a1 = rg[k][2 * j + 1]; }
            else {
                a0 = buf[64 + (j - 2) * 128 + lane];
                a1 = buf[64 + (j - 2) * 128 + 64 + lane];
            }
            float d = h0.x * a0.x;
            d = fmaf(h0.y, a0.y, d);
            d = fmaf(h0.z, a0.z, d);
            d = fmaf(h0.w, a0.w, d);
            float e2 = h1.x * a1.x;
            e2 = fmaf(h1.y, a1.y, e2);
            e2 = fmaf(h1.z, a1.z, e2);
            e2 = fmaf(h1.w, a1.w, e2);
            d += e2;
            d += __shfl_xor(d, 1, 64);
            d += __shfl_xor(d, 2, 64);
            d += __shfl_xor(d, 4, 64);
            d += __shfl_xor(d, 8, 64);
            const float x  = cd[k][j] * d;
            const float ls = fminf(x, 0.f) - __logf(1.f + __expf(-fabsf(x)));
            acc = fmaf(fabsf(cd[k][j]), ls, acc);
        }
    };

    // ---- prologue fill: meta(0), meta(1), G(0)
    issue_meta(0);
    issue_meta(1);
    __builtin_amdgcn_sched_barrier(0);
    issue_G(0);                       // auto-waits meta(0): vmcnt(10)
    __builtin_amdgcn_sched_barrier(0);

    // ---- steady-state pipeline
    #pragma unroll
    for (int k = 0; k < EPW; ++k) {
        if (k + 2 < EPW) issue_meta(k + 2);          // B: 10 loads
        __builtin_amdgcn_sched_barrier(0);           // pin B above
        if (k + 1 < EPW) issue_G(k + 1);             // G: 4 reg + 7 lds
        __builtin_amdgcn_sched_barrier(0);           // pin G above the wait
        // counted drain: gathers(k) done; B(k+2)+G(k+1) stay in flight
        if      (k < EPW - 2) __builtin_amdgcn_s_waitcnt(VMW(21));
        else if (k < EPW - 1) __builtin_amdgcn_s_waitcnt(VMW(11));
        else                  __builtin_amdgcn_s_waitcnt(VMW(0));
        __builtin_amdgcn_sched_barrier(0);           // no ds_read above wait
        do_compute(k);
    }

    // sum across the 4 groups (each lane already has its group total)
    acc += __shfl_xor(acc, 16, 64);
    acc += __shfl_xor(acc, 32, 64);

    if (lane == 0) ws[wave] = -acc;
    __syncthreads();
    if (threadIdx.x == 0) {
        partials[blockIdx.x] = ws[0] + ws[1];
    }
}

__global__ __launch_bounds__(256) void hs_reduce_kernel(
    const float* __restrict__ partials, float* __restrict__ out)
{
    const float4* p4 = (const float4*)partials;     // 256 float4 = 1024 floats
    const float4 v = p4[threadIdx.x];
    float s = (v.x + v.y) + (v.z + v.w);
    #pragma unroll
    for (int off = 32; off; off >>= 1) s += __shfl_xor(s, off, 64);
    __shared__ float ws[4];
    const int wave = threadIdx.x >> 6;
    const int lane = threadIdx.x & 63;
    if (lane == 0) ws[wave] = s;
    __syncthreads();
    if (threadIdx.x == 0) {
        out[0] = (ws[0] + ws[1] + ws[2] + ws[3]) / (float)BATCH;
    }
}

extern "C" void kernel_launch(void* const* d_in, const int* in_sizes, int n_in,
                              void* d_out, int out_size, void* d_ws, size_t ws_size,
                              hipStream_t stream) {
    const int*   center    = (const int*)d_in[0];
    const int*   target    = (const int*)d_in[1];
    const float* in_emb    = (const float*)d_in[2];
    const float* inner_vec = (const float*)d_in[3];
    const int*   paths     = (const int*)d_in[4];
    const float* codes     = (const float*)d_in[5];
    // d_in[6] (masks) intentionally unused: mask == |code|
    float* out = (float*)d_out;
    float* partials = (float*)d_ws;   // 1024 floats scratch

    hs_loss_kernel<<<NBLK, 128, 0, stream>>>(
        center, target, in_emb, inner_vec, paths, codes, partials);
    hs_reduce_kernel<<<1, 256, 0, stream>>>(partials, out);
}

// Round 3
// 158.582 us; speedup vs baseline: 1.0181x; 1.0181x over previous
//
#include <hip/hip_runtime.h>

#define VOCAB 100000
#define EMBED 128
#define MAX_PATH 20
#define BATCH 32768
#define WPB 4                    // waves per block (block = 256 threads)
#define NBLOCKS (BATCH / WPB)    // 8192

// R11: restore R8 champion (harness-verified 157.2us; best dispatch 40.8us).
// R9 (occupancy 52->66%) and R10 (deep per-wave pipeline, counted vmcnt)
// both left gather BW pinned at 2.7-3.1 TB/s => the limiter is the random
// 512B-row gather pattern itself (FETCH ~121MB: 51MB inner_vec with ~1.9x
// cross-XCD L2 duplication + 17MB in_emb + 10MB meta), not latency hiding.
// R8 structure:
//  - chunks 0,1 -> register gathers (compiler keeps ~2 in flight; R5)
//  - chunks 2,3,4 -> global_load_lds (un-sinkable, 0 VGPR; R6)
//  - per-wave s_waitcnt vmcnt(0) instead of __syncthreads: each wave's LDS
//    region is private, so no block-wide load-drain coupling
//  - 6 KB LDS/wave -> 24 KB/block -> 6 blocks/CU = 24 waves/CU
//  - chunks 3/4 skipped wave-uniformly when fully padded (P=38%/69%)
// Layout: every vmem instr is 256B-contiguous per 16-lane group; LDS stage
// obeys dest = uniform base + lane*16 (m104/m108), readback contiguous.
__global__ __launch_bounds__(256, 6) void hs_loss_kernel(
    const int* __restrict__ center, const int* __restrict__ target,
    const float* __restrict__ in_emb, const float* __restrict__ inner_vec,
    const int* __restrict__ paths, const float* __restrict__ codes,
    float* __restrict__ partials)
{
    __shared__ float4 lds_buf[WPB * 384];   // 3 chunks x 2 KB per wave
    __shared__ float  ws[WPB];

    const int wave = threadIdx.x >> 6;
    const int lane = threadIdx.x & 63;
    const int g    = lane >> 4;   // group 0..3
    const int gl   = lane & 15;   // lane within group
    const int b = blockIdx.x * WPB + wave;

    const int c = center[b];
    const int t = target[b];

    // h fragment (reused 5x): 256B-contiguous per instruction
    const float4* hp = (const float4*)(in_emb + (size_t)c * EMBED);
    const float4 h0 = hp[gl];
    const float4 h1 = hp[gl + 16];

    // Group g's 5 (path, code) pairs: nodes g, g+4, ..., g+16
    const int base = t * MAX_PATH + g;
    int   p[5];
    float cd[5];
    #pragma unroll
    for (int j = 0; j < 5; ++j) {
        p[j]  = paths[base + 4 * j];
        cd[j] = codes[base + 4 * j];
    }
    // wave-uniform chunk validity (all 4 groups share one path length)
    const bool do3 = __ballot(cd[3] != 0.f) != 0ull;
    const bool do4 = __ballot(cd[4] != 0.f) != 0ull;

    // register gathers: chunks 0,1
    const float4* v0 = (const float4*)(inner_vec + (size_t)p[0] * EMBED);
    const float4 r00 = v0[gl], r01 = v0[gl + 16];
    const float4* v1 = (const float4*)(inner_vec + (size_t)p[1] * EMBED);
    const float4 r10 = v1[gl], r11 = v1[gl + 16];

    // async LDS stages: chunks 2,3,4 (two 1024B instrs each)
    float4* myl = lds_buf + wave * 384;
    {
        const float* src = inner_vec + (size_t)p[2] * EMBED + 4 * gl;
        __builtin_amdgcn_global_load_lds(
            (const __attribute__((address_space(1))) unsigned int*)(src),
            (__attribute__((address_space(3))) unsigned int*)(myl),
            16, 0, 0);
        __builtin_amdgcn_global_load_lds(
            (const __attribute__((address_space(1))) unsigned int*)(src + 64),
            (__attribute__((address_space(3))) unsigned int*)(myl + 64),
            16, 0, 0);
    }
    if (do3) {
        const float* src = inner_vec + (size_t)p[3] * EMBED + 4 * gl;
        __builtin_amdgcn_global_load_lds(
            (const __attribute__((address_space(1))) unsigned int*)(src),
            (__attribute__((address_space(3))) unsigned int*)(myl + 128),
            16, 0, 0);
        __builtin_amdgcn_global_load_lds(
            (const __attribute__((address_space(1))) unsigned int*)(src + 64),
            (__attribute__((address_space(3))) unsigned int*)(myl + 192),
            16, 0, 0);
    }
    if (do4) {
        const float* src = inner_vec + (size_t)p[4] * EMBED + 4 * gl;
        __builtin_amdgcn_global_load_lds(
            (const __attribute__((address_space(1))) unsigned int*)(src),
            (__attribute__((address_space(3))) unsigned int*)(myl + 256),
            16, 0, 0);
        __builtin_amdgcn_global_load_lds(
            (const __attribute__((address_space(1))) unsigned int*)(src + 64),
            (__attribute__((address_space(3))) unsigned int*)(myl + 320),
            16, 0, 0);
    }

    float acc = 0.f;
    // ---- chunks 0,1 from registers (compiler inserts partial vmcnt waits)
    #pragma unroll
    for (int j = 0; j < 2; ++j) {
        const float4 a0 = (j == 0) ? r00 : r10;
        const float4 a1 = (j == 0) ? r01 : r11;
        float d = h0.x * a0.x;
        d = fmaf(h0.y, a0.y, d);
        d = fmaf(h0.z, a0.z, d);
        d = fmaf(h0.w, a0.w, d);
        float e = h1.x * a1.x;
        e = fmaf(h1.y, a1.y, e);
        e = fmaf(h1.z, a1.z, e);
        e = fmaf(h1.w, a1.w, e);
        d += e;
        d += __shfl_xor(d, 1, 64);
        d += __shfl_xor(d, 2, 64);
        d += __shfl_xor(d, 4, 64);
        d += __shfl_xor(d, 8, 64);
        const float x  = cd[j] * d;
        const float ls = fminf(x, 0.f) - __logf(1.f + __expf(-fabsf(x)));
        acc = fmaf(fabsf(cd[j]), ls, acc);
    }

    // ---- per-wave drain of my LDS stages (NOT a block barrier)
    __builtin_amdgcn_s_waitcnt(0xF70);      // vmcnt(0), lgkm/exp unconstrained
    __builtin_amdgcn_sched_barrier(0);      // pin: no ds_read hoisted above

    // ---- chunks 2,3,4 from LDS (contiguous ds_read_b128, conflict-free)
    #pragma unroll
    for (int j = 2; j < 5; ++j) {
        if (j == 3 && !do3) continue;       // wave-uniform skip (LDS garbage)
        if (j == 4 && !do4) continue;
        const float4 a0 = myl[(j - 2) * 128 + lane];
        const float4 a1 = myl[(j - 2) * 128 + 64 + lane];
        float d = h0.x * a0.x;
        d = fmaf(h0.y, a0.y, d);
        d = fmaf(h0.z, a0.z, d);
        d = fmaf(h0.w, a0.w, d);
        float e = h1.x * a1.x;
        e = fmaf(h1.y, a1.y, e);
        e = fmaf(h1.z, a1.z, e);
        e = fmaf(h1.w, a1.w, e);
        d += e;
        d += __shfl_xor(d, 1, 64);
        d += __shfl_xor(d, 2, 64);
        d += __shfl_xor(d, 4, 64);
        d += __shfl_xor(d, 8, 64);
        const float x  = cd[j] * d;
        const float ls = fminf(x, 0.f) - __logf(1.f + __expf(-fabsf(x)));
        acc = fmaf(fabsf(cd[j]), ls, acc);
    }

    // sum across the 4 groups
    acc += __shfl_xor(acc, 16, 64);
    acc += __shfl_xor(acc, 32, 64);

    if (lane == 0) ws[wave] = -acc;
    __syncthreads();
    if (threadIdx.x == 0) {
        partials[blockIdx.x] = ws[0] + ws[1] + ws[2] + ws[3];
    }
}

__global__ __launch_bounds__(256) void hs_reduce_kernel(
    const float* __restrict__ partials, float* __restrict__ out)
{
    const float4* p4 = (const float4*)partials;     // 2048 float4
    float s = 0.f;
    #pragma unroll
    for (int i = 0; i < NBLOCKS / 4 / 256; ++i) {
        const float4 v = p4[i * 256 + threadIdx.x];
        s += (v.x + v.y) + (v.z + v.w);
    }
    #pragma unroll
    for (int off = 32; off; off >>= 1) s += __shfl_xor(s, off, 64);
    __shared__ float ws[4];
    const int wave = threadIdx.x >> 6;
    const int lane = threadIdx.x & 63;
    if (lane == 0) ws[wave] = s;
    __syncthreads();
    if (threadIdx.x == 0) {
        out[0] = (ws[0] + ws[1] + ws[2] + ws[3]) / (float)BATCH;
    }
}

extern "C" void kernel_launch(void* const* d_in, const int* in_sizes, int n_in,
                              void* d_out, int out_size, void* d_ws, size_t ws_size,
                              hipStream_t stream) {
    const int*   center    = (const int*)d_in[0];
    const int*   target    = (const int*)d_in[1];
    const float* in_emb    = (const float*)d_in[2];
    const float* inner_vec = (const float*)d_in[3];
    const int*   paths     = (const int*)d_in[4];
    const float* codes     = (const float*)d_in[5];
    // d_in[6] (masks) intentionally unused: mask == |code|
    float* out = (float*)d_out;
    float* partials = (float*)d_ws;   // 8192 floats = 32 KB scratch

    hs_loss_kernel<<<NBLOCKS, 256, 0, stream>>>(
        center, target, in_emb, inner_vec, paths, codes, partials);
    hs_reduce_kernel<<<1, 256, 0, stream>>>(partials, out);
}